// Round 1
// baseline (3987.815 us; speedup 1.0000x reference)
//
#include <hip/hip_runtime.h>
#include <stdint.h>
#include <stddef.h>

// GRU: T=512, B=64, F=128, H=512, O=16. fp32 in/out, bf16 MFMA compute.
//
// Persistent-kernel design:
//   64 workgroups = 4 batch-groups (16 rows each) x 16 col-groups (32 h-cols each).
//   W_ih / W_hh slices live in VGPRs as pre-packed bf16 MFMA B-fragments (read once).
//   Per step: stage h(t-1) tile via global_load_lds -> MFMA (gates r,z,n; n keeps
//   x-part and h-part separate) -> fused gate elementwise with fp32 master h ->
//   write bf16 h slice to hs history -> device-scope atomic barrier per batch-group.
//   Final kernel: y = hs @ w_out^T + b_out via MFMA (M=32768, N=16, K=512).

#define T_LEN 512
#define B_SZ  64
#define F_DIM 128
#define H_DIM 512
#define O_DIM 16

#define NBG   4      // batch groups
#define NCG   16     // col-group workgroups per batch group
#define XT_PITCH 136 // x tile row pitch (bf16 elems), padded vs 128 to break bank conflicts
#define HT_PITCH 520 // h tile row pitch (bf16 elems), padded vs 512

typedef __attribute__((ext_vector_type(8))) short short8;
typedef __attribute__((ext_vector_type(4))) float floatx4;

__device__ __forceinline__ unsigned short f2bf(float f) {
  unsigned u = __builtin_bit_cast(unsigned, f);
  u += 0x7fffu + ((u >> 16) & 1u);   // round-to-nearest-even
  return (unsigned short)(u >> 16);
}

__device__ __forceinline__ float sigmoidf_(float x) {
  return 1.0f / (1.0f + __expf(-x));
}

// async global->LDS, 16B per lane; LDS dest must be wave-uniform base (+lane*16 implicit)
__device__ __forceinline__ void gload_lds16(const unsigned short* g, unsigned short* l) {
  __builtin_amdgcn_global_load_lds(
      (const __attribute__((address_space(1))) unsigned int*)g,
      (__attribute__((address_space(3))) unsigned int*)l, 16, 0, 0);
}

__global__ __launch_bounds__(256, 1)
void gru_persistent(const float* __restrict__ x,
                    const float* __restrict__ w_ih,
                    const float* __restrict__ w_hh,
                    const float* __restrict__ b_ih,
                    const float* __restrict__ b_hh,
                    unsigned short* __restrict__ hs,   // (T, B, H) bf16 history
                    unsigned int* __restrict__ counters) {
  __shared__ unsigned short x_tile[16 * XT_PITCH];   // 16 rows x 128 (+pad) bf16
  __shared__ unsigned short h_tile[16 * HT_PITCH];   // 16 rows x 512 (+pad) bf16
  __shared__ float hgL[4][16][33];                   // r, z, xn, hn pre-activations
  __shared__ float h_master[16][32];                 // fp32 master of own h cols

  const int tid  = threadIdx.x;
  const int lane = tid & 63;
  const int wv   = tid >> 6;          // wave 0..3 (0..2 = gates r,z,n)
  const int bg   = blockIdx.x >> 4;   // batch group 0..3
  const int cg   = blockIdx.x & 15;   // col group 0..15
  const int bgbase  = bg * 16;        // first batch row
  const int colbase = cg * 32;        // first owned h column

  const int n16  = lane & 15;
  const int quad = lane >> 4;

  // ---- preload B fragments (bf16) into registers: W read from HBM exactly once ----
  short8 bwx[2][4];    // w_ih slice: 2 N-tiles x 4 K-chunks (K=128)
  short8 bwh[2][16];   // w_hh slice: 2 N-tiles x 16 K-chunks (K=512)
  if (wv < 3) {
    #pragma unroll
    for (int nt = 0; nt < 2; ++nt) {
      const int grow = wv * H_DIM + colbase + nt * 16 + n16;  // gate-row of W
      const float* pih = w_ih + (size_t)grow * F_DIM + quad * 8;
      #pragma unroll
      for (int kc = 0; kc < 4; ++kc) {
        short8 v;
        #pragma unroll
        for (int j = 0; j < 8; ++j) v[j] = (short)f2bf(pih[kc * 32 + j]);
        bwx[nt][kc] = v;
      }
      const float* phh = w_hh + (size_t)grow * H_DIM + quad * 8;
      #pragma unroll
      for (int kc = 0; kc < 16; ++kc) {
        short8 v;
        #pragma unroll
        for (int j = 0; j < 8; ++j) v[j] = (short)f2bf(phh[kc * 32 + j]);
        bwh[nt][kc] = v;
      }
    }
  }

  // ---- per-thread biases for the 2 owned (b, col) elementwise items ----
  const int ew_b  = tid >> 4;          // batch row 0..15
  const int ew_j0 = (tid & 15) * 2;    // first of 2 adjacent owned cols
  float b_rz[2], b_zz[2], b_in[2], b_hn[2];
  #pragma unroll
  for (int e = 0; e < 2; ++e) {
    const int c = colbase + ew_j0 + e;
    b_rz[e] = b_ih[c] + b_hh[c];
    b_zz[e] = b_ih[H_DIM + c] + b_hh[H_DIM + c];
    b_in[e] = b_ih[2 * H_DIM + c];
    b_hn[e] = b_hh[2 * H_DIM + c];
  }

  // ---- zero h tile (h0 = 0) and fp32 master ----
  for (int i = tid; i < 16 * HT_PITCH; i += 256) h_tile[i] = 0;
  for (int i = tid; i < 16 * 32; i += 256) (&h_master[0][0])[i] = 0.0f;
  __syncthreads();

  unsigned int* cnt = counters + bg * 64;  // 256B-separated per batch group

  for (int t = 0; t < T_LEN; ++t) {
    // ---- stage x[t] tile: 16 rows x 128 fp32 -> bf16 LDS ----
    {
      const int row = tid >> 4, c8 = (tid & 15) * 8;
      const float* px = x + ((size_t)(t * B_SZ + bgbase + row)) * F_DIM + c8;
      floatx4 f0 = *(const floatx4*)px;
      floatx4 f1 = *(const floatx4*)(px + 4);
      short8 v;
      v[0] = (short)f2bf(f0[0]); v[1] = (short)f2bf(f0[1]);
      v[2] = (short)f2bf(f0[2]); v[3] = (short)f2bf(f0[3]);
      v[4] = (short)f2bf(f1[0]); v[5] = (short)f2bf(f1[1]);
      v[6] = (short)f2bf(f1[2]); v[7] = (short)f2bf(f1[3]);
      *(short8*)&x_tile[row * XT_PITCH + c8] = v;
    }
    // ---- stage h(t-1) tile: 16 rows x 512 bf16 via async global->LDS ----
    if (t > 0) {
      #pragma unroll
      for (int r4 = 0; r4 < 4; ++r4) {
        const int row = wv * 4 + r4;
        const unsigned short* g =
            hs + ((size_t)((t - 1) * B_SZ + bgbase + row)) * H_DIM + lane * 8;
        gload_lds16(g, &h_tile[row * HT_PITCH]);
      }
    }
    __syncthreads();  // drains vmcnt/lgkmcnt: tiles ready

    // ---- MFMA phase: waves 0..2 compute their gate's 16x32 pre-activation ----
    if (wv < 3) {
      floatx4 acc0 = {0.f, 0.f, 0.f, 0.f};  // r/z: combined x+h; n: x-part, nt=0
      floatx4 acc1 = {0.f, 0.f, 0.f, 0.f};  // r/z: combined x+h; n: x-part, nt=1
      floatx4 acc2 = {0.f, 0.f, 0.f, 0.f};  // n: h-part, nt=0
      floatx4 acc3 = {0.f, 0.f, 0.f, 0.f};  // n: h-part, nt=1
      #pragma unroll
      for (int kc = 0; kc < 4; ++kc) {
        short8 a = *(const short8*)&x_tile[n16 * XT_PITCH + kc * 32 + quad * 8];
        acc0 = __builtin_amdgcn_mfma_f32_16x16x32_bf16(a, bwx[0][kc], acc0, 0, 0, 0);
        acc1 = __builtin_amdgcn_mfma_f32_16x16x32_bf16(a, bwx[1][kc], acc1, 0, 0, 0);
      }
      if (wv == 2) {
        #pragma unroll
        for (int kc = 0; kc < 16; ++kc) {
          short8 a = *(const short8*)&h_tile[n16 * HT_PITCH + kc * 32 + quad * 8];
          acc2 = __builtin_amdgcn_mfma_f32_16x16x32_bf16(a, bwh[0][kc], acc2, 0, 0, 0);
          acc3 = __builtin_amdgcn_mfma_f32_16x16x32_bf16(a, bwh[1][kc], acc3, 0, 0, 0);
        }
      } else {
        #pragma unroll
        for (int kc = 0; kc < 16; ++kc) {
          short8 a = *(const short8*)&h_tile[n16 * HT_PITCH + kc * 32 + quad * 8];
          acc0 = __builtin_amdgcn_mfma_f32_16x16x32_bf16(a, bwh[0][kc], acc0, 0, 0, 0);
          acc1 = __builtin_amdgcn_mfma_f32_16x16x32_bf16(a, bwh[1][kc], acc1, 0, 0, 0);
        }
      }
      // D layout: col = lane&15, row = quad*4 + reg
      #pragma unroll
      for (int i = 0; i < 4; ++i) {
        const int r = quad * 4 + i;
        if (wv == 2) {
          hgL[2][r][n16]      = acc0[i];
          hgL[2][r][16 + n16] = acc1[i];
          hgL[3][r][n16]      = acc2[i];
          hgL[3][r][16 + n16] = acc3[i];
        } else {
          hgL[wv][r][n16]      = acc0[i];
          hgL[wv][r][16 + n16] = acc1[i];
        }
      }
    }
    __syncthreads();

    // ---- fused gate elementwise: each thread owns 2 adjacent (b, col) items ----
    {
      unsigned short hb[2];
      #pragma unroll
      for (int e = 0; e < 2; ++e) {
        const int c = ew_j0 + e;
        const float r = sigmoidf_(hgL[0][ew_b][c] + b_rz[e]);
        const float z = sigmoidf_(hgL[1][ew_b][c] + b_zz[e]);
        const float n = tanhf(hgL[2][ew_b][c] + b_in[e] + r * (hgL[3][ew_b][c] + b_hn[e]));
        const float hp = h_master[ew_b][c];
        const float hn2 = (1.0f - z) * n + z * hp;
        h_master[ew_b][c] = hn2;  // fp32 carry path: no bf16 random-walk
        hb[e] = f2bf(hn2);
      }
      const unsigned int packed = ((unsigned int)hb[1] << 16) | (unsigned int)hb[0];
      *(unsigned int*)(hs + ((size_t)(t * B_SZ + bgbase + ew_b)) * H_DIM + colbase + ew_j0) =
          packed;
    }
    __threadfence();   // release h slice device-wide (cross-XCD L2 writeback)
    __syncthreads();   // all stores + fences in this wg complete

    // ---- batch-group barrier: monotonic device-scope counter ----
    if (tid == 0) {
      __hip_atomic_fetch_add(cnt, 1u, __ATOMIC_RELEASE, __HIP_MEMORY_SCOPE_AGENT);
      const unsigned int target = (unsigned int)(NCG * (t + 1));
      while (__hip_atomic_load(cnt, __ATOMIC_ACQUIRE, __HIP_MEMORY_SCOPE_AGENT) < target)
        __builtin_amdgcn_s_sleep(1);
    }
    __syncthreads();   // whole wg proceeds with invalidated caches (acquire done by tid0)
  }
}

// y = hs @ w_out^T + b_out : flat GEMM M=T*B=32768, N=16, K=512
__global__ __launch_bounds__(64, 1)
void gru_proj(const unsigned short* __restrict__ hs,
              const float* __restrict__ w_out,
              const float* __restrict__ b_out,
              float* __restrict__ y) {
  __shared__ unsigned short tile[16 * HT_PITCH];
  const int lane = threadIdx.x;
  const int n16  = lane & 15;
  const int quad = lane >> 4;
  const size_t rowbase = (size_t)blockIdx.x * 16;

  short8 bw[16];
  const float* pw = w_out + (size_t)n16 * H_DIM + quad * 8;
  #pragma unroll
  for (int kc = 0; kc < 16; ++kc) {
    short8 v;
    #pragma unroll
    for (int j = 0; j < 8; ++j) v[j] = (short)f2bf(pw[kc * 32 + j]);
    bw[kc] = v;
  }
  const float bo = b_out[n16];

  #pragma unroll
  for (int r = 0; r < 16; ++r)
    gload_lds16(hs + (rowbase + r) * H_DIM + lane * 8, &tile[r * HT_PITCH]);
  asm volatile("s_waitcnt vmcnt(0)" ::: "memory");
  __syncthreads();

  floatx4 acc = {0.f, 0.f, 0.f, 0.f};
  #pragma unroll
  for (int kc = 0; kc < 16; ++kc) {
    short8 a = *(const short8*)&tile[n16 * HT_PITCH + kc * 32 + quad * 8];
    acc = __builtin_amdgcn_mfma_f32_16x16x32_bf16(a, bw[kc], acc, 0, 0, 0);
  }
  #pragma unroll
  for (int i = 0; i < 4; ++i) {
    const int r = quad * 4 + i;
    y[(rowbase + r) * O_DIM + n16] = acc[i] + bo;
  }
}

extern "C" void kernel_launch(void* const* d_in, const int* in_sizes, int n_in,
                              void* d_out, int out_size, void* d_ws, size_t ws_size,
                              hipStream_t stream) {
  (void)in_sizes; (void)n_in; (void)out_size; (void)ws_size;
  const float* x     = (const float*)d_in[0];
  const float* w_ih  = (const float*)d_in[1];
  const float* w_hh  = (const float*)d_in[2];
  const float* b_ih  = (const float*)d_in[3];
  const float* b_hh  = (const float*)d_in[4];
  const float* w_out = (const float*)d_in[5];
  const float* b_out = (const float*)d_in[6];
  float* y = (float*)d_out;

  unsigned int*   counters = (unsigned int*)d_ws;
  unsigned short* hs = (unsigned short*)((char*)d_ws + 4096);  // 32 MB bf16 history

  hipMemsetAsync(d_ws, 0, 4096, stream);  // zero barrier counters (ws is poisoned)
  gru_persistent<<<NBG * NCG, 256, 0, stream>>>(x, w_ih, w_hh, b_ih, b_hh, hs, counters);
  gru_proj<<<(T_LEN * B_SZ) / 16, 64, 0, stream>>>(hs, w_out, b_out, y);
}

// Round 2
// 1533.544 us; speedup vs baseline: 2.6004x; 2.6004x over previous
//
#include <hip/hip_runtime.h>
#include <stdint.h>
#include <stddef.h>

// GRU: T=512, B=64, F=128, H=512, O=16. fp32 in/out, bf16 MFMA compute.
//
// Persistent-kernel design (R2):
//   64 workgroups = 4 batch-groups (16 rows each) x 16 col-groups (32 h-cols each).
//   W_ih / W_hh slices live in VGPRs as pre-packed bf16 MFMA B-fragments (read once).
//   Cross-wg h exchange uses PER-ACCESS device-scope (sc1) memory ops at the LLC —
//   no __threadfence / no whole-L2 writeback+invalidate per step (R1's 7.6us/step bug).
//   Per step: issue x loads early -> spin on batch-group counter (relaxed agent) ->
//   global_load_lds h(t-1) with aux=SC1 -> MFMA gates r,z,n -> fused elementwise with
//   fp32 master h -> device-scope h store -> s_waitcnt vmcnt(0) -> relaxed agent add.

#define T_LEN 512
#define B_SZ  64
#define F_DIM 128
#define H_DIM 512
#define O_DIM 16

#define NBG   4      // batch groups
#define NCG   16     // col-group workgroups per batch group
#define XT_PITCH 136 // x tile row pitch (bf16 elems), padded vs 128
#define HT_PITCH 520 // h tile row pitch (bf16 elems), padded vs 512

// CPol aux bits (gfx950): SC0=1, NT=2, SC1=16. Device scope = SC1.
#define AUX_DEVICE_SCOPE 16

typedef __attribute__((ext_vector_type(8))) short short8;
typedef __attribute__((ext_vector_type(4))) float floatx4;

__device__ __forceinline__ unsigned short f2bf(float f) {
  unsigned u = __builtin_bit_cast(unsigned, f);
  u += 0x7fffu + ((u >> 16) & 1u);   // round-to-nearest-even
  return (unsigned short)(u >> 16);
}

__device__ __forceinline__ float sigmoidf_(float x) {
  return 1.0f / (1.0f + __expf(-x));
}

// async global->LDS, 16B per lane, device-scope (coherent at LLC)
__device__ __forceinline__ void gload_lds16_dev(const unsigned short* g, unsigned short* l) {
  __builtin_amdgcn_global_load_lds(
      (const __attribute__((address_space(1))) unsigned int*)g,
      (__attribute__((address_space(3))) unsigned int*)l, 16, 0, AUX_DEVICE_SCOPE);
}

__device__ __forceinline__ void gload_lds16(const unsigned short* g, unsigned short* l) {
  __builtin_amdgcn_global_load_lds(
      (const __attribute__((address_space(1))) unsigned int*)g,
      (__attribute__((address_space(3))) unsigned int*)l, 16, 0, 0);
}

__global__ __launch_bounds__(256, 1)
void gru_persistent(const float* __restrict__ x,
                    const float* __restrict__ w_ih,
                    const float* __restrict__ w_hh,
                    const float* __restrict__ b_ih,
                    const float* __restrict__ b_hh,
                    unsigned short* __restrict__ hs,   // (T, B, H) bf16 history
                    unsigned int* __restrict__ counters) {
  __shared__ unsigned short x_tile[16 * XT_PITCH];   // 16 rows x 128 (+pad) bf16
  __shared__ unsigned short h_tile[16 * HT_PITCH];   // 16 rows x 512 (+pad) bf16
  __shared__ float hgL[4][16][33];                   // r, z, xn, hn pre-activations
  __shared__ float h_master[16][32];                 // fp32 master of own h cols

  const int tid  = threadIdx.x;
  const int lane = tid & 63;
  const int wv   = tid >> 6;          // wave 0..3 (0..2 = gates r,z,n)
  const int bg   = blockIdx.x >> 4;   // batch group 0..3
  const int cg   = blockIdx.x & 15;   // col group 0..15
  const int bgbase  = bg * 16;        // first batch row
  const int colbase = cg * 32;        // first owned h column

  const int n16  = lane & 15;
  const int quad = lane >> 4;

  // ---- preload B fragments (bf16) into registers: W read from HBM exactly once ----
  short8 bwx[2][4];    // w_ih slice: 2 N-tiles x 4 K-chunks (K=128)
  short8 bwh[2][16];   // w_hh slice: 2 N-tiles x 16 K-chunks (K=512)
  if (wv < 3) {
    #pragma unroll
    for (int nt = 0; nt < 2; ++nt) {
      const int grow = wv * H_DIM + colbase + nt * 16 + n16;  // gate-row of W
      const float* pih = w_ih + (size_t)grow * F_DIM + quad * 8;
      #pragma unroll
      for (int kc = 0; kc < 4; ++kc) {
        short8 v;
        #pragma unroll
        for (int j = 0; j < 8; ++j) v[j] = (short)f2bf(pih[kc * 32 + j]);
        bwx[nt][kc] = v;
      }
      const float* phh = w_hh + (size_t)grow * H_DIM + quad * 8;
      #pragma unroll
      for (int kc = 0; kc < 16; ++kc) {
        short8 v;
        #pragma unroll
        for (int j = 0; j < 8; ++j) v[j] = (short)f2bf(phh[kc * 32 + j]);
        bwh[nt][kc] = v;
      }
    }
  }

  // ---- per-thread biases for the 2 owned (b, col) elementwise items ----
  const int ew_b  = tid >> 4;          // batch row 0..15
  const int ew_j0 = (tid & 15) * 2;    // first of 2 adjacent owned cols
  float b_rz[2], b_zz[2], b_in[2], b_hn[2];
  #pragma unroll
  for (int e = 0; e < 2; ++e) {
    const int c = colbase + ew_j0 + e;
    b_rz[e] = b_ih[c] + b_hh[c];
    b_zz[e] = b_ih[H_DIM + c] + b_hh[H_DIM + c];
    b_in[e] = b_ih[2 * H_DIM + c];
    b_hn[e] = b_hh[2 * H_DIM + c];
  }

  // ---- zero h tile (h0 = 0) and fp32 master ----
  for (int i = tid; i < 16 * HT_PITCH; i += 256) h_tile[i] = 0;
  for (int i = tid; i < 16 * 32; i += 256) (&h_master[0][0])[i] = 0.0f;
  __syncthreads();

  unsigned int* cnt = counters + bg * 64;  // 256B-separated per batch group

  const int xrow = tid >> 4, xc8 = (tid & 15) * 8;

  for (int t = 0; t < T_LEN; ++t) {
    // ---- issue x[t] loads early (normal cached loads; in flight during spin) ----
    const float* px = x + ((size_t)(t * B_SZ + bgbase + xrow)) * F_DIM + xc8;
    floatx4 f0 = *(const floatx4*)px;
    floatx4 f1 = *(const floatx4*)(px + 4);

    if (t > 0) {
      // ---- wait for all 16 wgs of this batch group to have published h(t-1) ----
      if (tid == 0) {
        const unsigned int target = (unsigned int)(NCG * t);
        while (__hip_atomic_load(cnt, __ATOMIC_RELAXED, __HIP_MEMORY_SCOPE_AGENT) < target)
          __builtin_amdgcn_s_sleep(1);
      }
      __syncthreads();
      // ---- stage h(t-1) tile: 16 rows x 512 bf16, device-scope async global->LDS ----
      #pragma unroll
      for (int r4 = 0; r4 < 4; ++r4) {
        const int row = wv * 4 + r4;
        const unsigned short* g =
            hs + ((size_t)((t - 1) * B_SZ + bgbase + row)) * H_DIM + lane * 8;
        gload_lds16_dev(g, &h_tile[row * HT_PITCH]);
      }
    }

    // ---- x fp32 -> bf16 LDS ----
    {
      short8 v;
      v[0] = (short)f2bf(f0[0]); v[1] = (short)f2bf(f0[1]);
      v[2] = (short)f2bf(f0[2]); v[3] = (short)f2bf(f0[3]);
      v[4] = (short)f2bf(f1[0]); v[5] = (short)f2bf(f1[1]);
      v[6] = (short)f2bf(f1[2]); v[7] = (short)f2bf(f1[3]);
      *(short8*)&x_tile[xrow * XT_PITCH + xc8] = v;
    }
    __syncthreads();  // full vmcnt/lgkmcnt drain: tiles ready

    // ---- MFMA phase: waves 0..2 compute their gate's 16x32 pre-activation ----
    if (wv < 3) {
      floatx4 acc0 = {0.f, 0.f, 0.f, 0.f};  // r/z: combined x+h; n: x-part, nt=0
      floatx4 acc1 = {0.f, 0.f, 0.f, 0.f};  // r/z: combined x+h; n: x-part, nt=1
      floatx4 acc2 = {0.f, 0.f, 0.f, 0.f};  // n: h-part, nt=0
      floatx4 acc3 = {0.f, 0.f, 0.f, 0.f};  // n: h-part, nt=1
      #pragma unroll
      for (int kc = 0; kc < 4; ++kc) {
        short8 a = *(const short8*)&x_tile[n16 * XT_PITCH + kc * 32 + quad * 8];
        acc0 = __builtin_amdgcn_mfma_f32_16x16x32_bf16(a, bwx[0][kc], acc0, 0, 0, 0);
        acc1 = __builtin_amdgcn_mfma_f32_16x16x32_bf16(a, bwx[1][kc], acc1, 0, 0, 0);
      }
      if (wv == 2) {
        #pragma unroll
        for (int kc = 0; kc < 16; ++kc) {
          short8 a = *(const short8*)&h_tile[n16 * HT_PITCH + kc * 32 + quad * 8];
          acc2 = __builtin_amdgcn_mfma_f32_16x16x32_bf16(a, bwh[0][kc], acc2, 0, 0, 0);
          acc3 = __builtin_amdgcn_mfma_f32_16x16x32_bf16(a, bwh[1][kc], acc3, 0, 0, 0);
        }
      } else {
        #pragma unroll
        for (int kc = 0; kc < 16; ++kc) {
          short8 a = *(const short8*)&h_tile[n16 * HT_PITCH + kc * 32 + quad * 8];
          acc0 = __builtin_amdgcn_mfma_f32_16x16x32_bf16(a, bwh[0][kc], acc0, 0, 0, 0);
          acc1 = __builtin_amdgcn_mfma_f32_16x16x32_bf16(a, bwh[1][kc], acc1, 0, 0, 0);
        }
      }
      // D layout: col = lane&15, row = quad*4 + reg
      #pragma unroll
      for (int i = 0; i < 4; ++i) {
        const int r = quad * 4 + i;
        if (wv == 2) {
          hgL[2][r][n16]      = acc0[i];
          hgL[2][r][16 + n16] = acc1[i];
          hgL[3][r][n16]      = acc2[i];
          hgL[3][r][16 + n16] = acc3[i];
        } else {
          hgL[wv][r][n16]      = acc0[i];
          hgL[wv][r][16 + n16] = acc1[i];
        }
      }
    }
    __syncthreads();

    // ---- fused gate elementwise: each thread owns 2 adjacent (b, col) items ----
    {
      unsigned short hb[2];
      #pragma unroll
      for (int e = 0; e < 2; ++e) {
        const int c = ew_j0 + e;
        const float r = sigmoidf_(hgL[0][ew_b][c] + b_rz[e]);
        const float z = sigmoidf_(hgL[1][ew_b][c] + b_zz[e]);
        const float n = tanhf(hgL[2][ew_b][c] + b_in[e] + r * (hgL[3][ew_b][c] + b_hn[e]));
        const float hp = h_master[ew_b][c];
        const float hn2 = (1.0f - z) * n + z * hp;
        h_master[ew_b][c] = hn2;  // fp32 carry path: no bf16 random-walk
        hb[e] = f2bf(hn2);
      }
      const unsigned int packed = ((unsigned int)hb[1] << 16) | (unsigned int)hb[0];
      unsigned int* dst = (unsigned int*)(hs +
          ((size_t)(t * B_SZ + bgbase + ew_b)) * H_DIM + colbase + ew_j0);
      // device-scope store: write-through to LLC, no cache-maintenance fence needed
      __hip_atomic_store(dst, packed, __ATOMIC_RELAXED, __HIP_MEMORY_SCOPE_AGENT);
    }
    asm volatile("s_waitcnt vmcnt(0)" ::: "memory");  // h stores acked at coherence point
    __syncthreads();                                  // all 256 threads' stores done

    // ---- publish arrival (relaxed: ordering already enforced by waitcnt) ----
    if (tid == 0)
      __hip_atomic_fetch_add(cnt, 1u, __ATOMIC_RELAXED, __HIP_MEMORY_SCOPE_AGENT);
  }
}

// y = hs @ w_out^T + b_out : flat GEMM M=T*B=32768, N=16, K=512
__global__ __launch_bounds__(64, 1)
void gru_proj(const unsigned short* __restrict__ hs,
              const float* __restrict__ w_out,
              const float* __restrict__ b_out,
              float* __restrict__ y) {
  __shared__ unsigned short tile[16 * HT_PITCH];
  const int lane = threadIdx.x;
  const int n16  = lane & 15;
  const int quad = lane >> 4;
  const size_t rowbase = (size_t)blockIdx.x * 16;

  short8 bw[16];
  const float* pw = w_out + (size_t)n16 * H_DIM + quad * 8;
  #pragma unroll
  for (int kc = 0; kc < 16; ++kc) {
    short8 v;
    #pragma unroll
    for (int j = 0; j < 8; ++j) v[j] = (short)f2bf(pw[kc * 32 + j]);
    bw[kc] = v;
  }
  const float bo = b_out[n16];

  #pragma unroll
  for (int r = 0; r < 16; ++r)
    gload_lds16(hs + (rowbase + r) * H_DIM + lane * 8, &tile[r * HT_PITCH]);
  asm volatile("s_waitcnt vmcnt(0)" ::: "memory");
  __syncthreads();

  floatx4 acc = {0.f, 0.f, 0.f, 0.f};
  #pragma unroll
  for (int kc = 0; kc < 16; ++kc) {
    short8 a = *(const short8*)&tile[n16 * HT_PITCH + kc * 32 + quad * 8];
    acc = __builtin_amdgcn_mfma_f32_16x16x32_bf16(a, bw[kc], acc, 0, 0, 0);
  }
  #pragma unroll
  for (int i = 0; i < 4; ++i) {
    const int r = quad * 4 + i;
    y[(rowbase + r) * O_DIM + n16] = acc[i] + bo;
  }
}

extern "C" void kernel_launch(void* const* d_in, const int* in_sizes, int n_in,
                              void* d_out, int out_size, void* d_ws, size_t ws_size,
                              hipStream_t stream) {
  (void)in_sizes; (void)n_in; (void)out_size; (void)ws_size;
  const float* x     = (const float*)d_in[0];
  const float* w_ih  = (const float*)d_in[1];
  const float* w_hh  = (const float*)d_in[2];
  const float* b_ih  = (const float*)d_in[3];
  const float* b_hh  = (const float*)d_in[4];
  const float* w_out = (const float*)d_in[5];
  const float* b_out = (const float*)d_in[6];
  float* y = (float*)d_out;

  unsigned int*   counters = (unsigned int*)d_ws;
  unsigned short* hs = (unsigned short*)((char*)d_ws + 4096);  // 32 MB bf16 history

  hipMemsetAsync(d_ws, 0, 4096, stream);  // zero barrier counters (ws is poisoned)
  gru_persistent<<<NBG * NCG, 256, 0, stream>>>(x, w_ih, w_hh, b_ih, b_hh, hs, counters);
  gru_proj<<<(T_LEN * B_SZ) / 16, 64, 0, stream>>>(hs, w_out, b_out, y);
}